// Round 12
// baseline (866.521 us; speedup 1.0000x reference)
//
#include <hip/hip_runtime.h>
#include <math.h>

#define NCLS 9

typedef __attribute__((ext_vector_type(8))) short short8;
typedef __attribute__((ext_vector_type(4))) float f32x4;

__device__ __forceinline__ unsigned short f2bf(float f) {
    unsigned int u = __float_as_uint(f);
    return (unsigned short)((u + 0x7fffu + ((u >> 16) & 1u)) >> 16);  // RNE
}

__device__ __forceinline__ short8 as_s8(uint4 v) {
    union { uint4 u; short8 s; } x; x.u = v; return x.s;
}

__device__ __forceinline__ float fast_tanh(float x) {
    // tanh(x) = 1 - 2/(2^(x*2*log2e) + 1); saturates correctly at +/-1
    float s = x * 2.885390081777927f;
    float e, r;
    asm("v_exp_f32 %0, %1" : "=v"(e) : "v"(s));
    asm("v_rcp_f32 %0, %1" : "=v"(r) : "v"(e + 1.0f));
    return fmaf(-2.0f, r, 1.0f);
}

// Fused 2-layer persistent MFMA RNN, M=2 rows/block, 256 blocks, K-SPLIT.
// 512 threads (8 waves = 4 pairs). Pair wp = w&3 owns 64 cols; hi = w>>2
// selects the K-half: lo wave K=[0,128) + input-projection, hi wave
// K=[128,256). Each wave reads only its half of h: 4 ds_read_b128 (vs 8) --
// the dominant DS-datapath term halves (A-reads 64->32 instrs/CU-step).
// hi hands its partial sums to lo via a 2KB pbuf (16-lane b128 writes,
// ~free) with a second barrier.
//
// Wave tile map: tile (u,v): col = wp*64 + u*32 + 2c + v (c = lane&15);
// bfrag = 16 uint4 = 64 VGPR (the proven-resident count, 2 waves/SIMD).
//
// ROW-DUPLICATION (R11): lane (g,l16) reads A row (l16&1); 8 lanes share
// each address (broadcast); C rows 2..15 are consistent duplicates.
//
// h LDS: 64 cells x 16B per buffer; cell (kk,g2,m) = idx kk*8+g2*2+m holds
// k = kk*32+g2*8+0..7 of row m. A-read: 8 distinct cells/instr, x8 bcast.
// h-write (lo, g==0): b32, 16 distinct banks, conflict-free.
__global__ __launch_bounds__(512, 2) void rnn_fused_kernel(
    const float* __restrict__ x,     // [B, 1024]
    const float* __restrict__ W1, const float* __restrict__ U1, const float* __restrict__ b1,
    const float* __restrict__ W2, const float* __restrict__ U2, const float* __restrict__ b2,
    float* __restrict__ h2out)       // [B, 256]
{
    const int tid  = threadIdx.x;
    const int w    = tid >> 6;
    const int lane = tid & 63;
    const int g    = lane >> 4;
    const int l16  = lane & 15;
    const int wp   = w & 3;      // column pair-group
    const int hi   = w >> 2;     // K-half
    const int b0   = blockIdx.x << 1;   // 2 rows per block

    __shared__ uint4  hbuf[2][64];    // 2 x 1KB h double-buffer (cell layout)
    __shared__ float2 xall[1024];     // 8KB: x staged [t]{row0,row1}
    __shared__ float2 seq2[256];      // 2KB: layer-2 input [col]{row0,row1}
    __shared__ float4 pbuf[4][2][16]; // 2KB: hi-half partials [wp][u][c]

    // ---- stage all of x (once) + zero both h buffers ----
    {
        const float4* x4 = (const float4*)x;
        const int row = tid >> 8, tq = tid & 255;      // 512 threads = 2x256
        const float4 v = x4[(b0 + row) * 256 + tq];
        ((float*)&xall[tq * 4 + 0])[row] = v.x;
        ((float*)&xall[tq * 4 + 1])[row] = v.y;
        ((float*)&xall[tq * 4 + 2])[row] = v.z;
        ((float*)&xall[tq * 4 + 3])[row] = v.w;
        ((unsigned int*)hbuf)[tid] = 0u;               // 512 u32 = both buffers
    }

    // ---- hoisted LDS byte offsets ----
    int rd_off[4];
    #pragma unroll
    for (int kkl = 0; kkl < 4; ++kkl)
        rd_off[kkl] = (((hi * 4 + kkl) * 8) + g * 2 + (l16 & 1)) << 4;
    int wr_off[2][2];   // [u][row m]
    #pragma unroll
    for (int u = 0; u < 2; ++u)
        #pragma unroll
        for (int m = 0; m < 2; ++m)
            wr_off[u][m] = (((2 * wp + u) * 8 + ((2 * l16 >> 3) & 3) * 2 + m) << 4)
                         + 4 * (l16 & 3);
    char* const hbase = (char*)hbuf;

#pragma unroll 1
    for (int p = 0; p < 2; ++p) {
        const float* W    = p ? W2 : W1;
        const float* U    = p ? U2 : U1;
        const float* bias = p ? b2 : b1;
        const int    T    = p ? 256 : 1024;

        // ---- B-fragments: tile (u,v), this wave's K-half only ----
        uint4 bfrag[2][2][4];
        #pragma unroll
        for (int u = 0; u < 2; ++u) {
            #pragma unroll
            for (int v = 0; v < 2; ++v) {
                const int col = wp * 64 + u * 32 + 2 * l16 + v;
                #pragma unroll
                for (int kkl = 0; kkl < 4; ++kkl) {
                    unsigned int d[4];
                    #pragma unroll
                    for (int pr = 0; pr < 4; ++pr) {
                        const int k0 = (hi * 4 + kkl) * 32 + g * 8 + 2 * pr;
                        d[pr] = (unsigned)f2bf(U[k0 * 256 + col])
                              | ((unsigned)f2bf(U[(k0 + 1) * 256 + col]) << 16);
                    }
                    bfrag[u][v][kkl] = make_uint4(d[0], d[1], d[2], d[3]);
                }
            }
        }
        #pragma unroll
        for (int u = 0; u < 2; ++u)
            #pragma unroll
            for (int v = 0; v < 2; ++v)
                #pragma unroll
                for (int kkl = 0; kkl < 4; ++kkl)
                    asm volatile("" : "+v"(bfrag[u][v][kkl].x), "+v"(bfrag[u][v][kkl].y),
                                      "+v"(bfrag[u][v][kkl].z), "+v"(bfrag[u][v][kkl].w));

        // W/bias for this pair's cols (used by lo wave only)
        const float2 wv[2] = { *(const float2*)&W[wp * 64 + 2 * l16],
                               *(const float2*)&W[wp * 64 + 32 + 2 * l16] };
        const float2 bv[2] = { *(const float2*)&bias[wp * 64 + 2 * l16],
                               *(const float2*)&bias[wp * 64 + 32 + 2 * l16] };

        if (p == 1) {
            // re-zero h buffer 0 for layer 2 (first 1KB = 256 u32)
            if (tid < 256) ((unsigned int*)hbuf)[tid] = 0u;
        }
        __syncthreads();

        // sv prefetch for t=0 (uniform address, static LDS)
        float2 svc = p ? seq2[0] : xall[0];

        for (int t = 0; t < T; ++t) {
            char* const hcur = hbase + ((t & 1) << 10);
            char* const hnxt = hbase + (((t & 1) ^ 1) << 10);

            // A-fragments (own K-half): 4 x ds_read_b128, x8 broadcast
            uint4 a[4];
            #pragma unroll
            for (int kkl = 0; kkl < 4; ++kkl)
                a[kkl] = *(const uint4*)(hcur + rd_off[kkl]);

            // acc init: lo wave carries input projection + bias (rows 2..15
            // mirror 0..1); hi wave starts at zero.
            f32x4 acc[2][2];
            if (hi == 0) {
                #pragma unroll
                for (int u = 0; u < 2; ++u) {
                    acc[u][0][0] = fmaf(svc.x, wv[u].x, bv[u].x);
                    acc[u][0][1] = fmaf(svc.y, wv[u].x, bv[u].x);
                    acc[u][0][2] = acc[u][0][0]; acc[u][0][3] = acc[u][0][1];
                    acc[u][1][0] = fmaf(svc.x, wv[u].y, bv[u].y);
                    acc[u][1][1] = fmaf(svc.y, wv[u].y, bv[u].y);
                    acc[u][1][2] = acc[u][1][0]; acc[u][1][3] = acc[u][1][1];
                }
            } else {
                #pragma unroll
                for (int u = 0; u < 2; ++u)
                    #pragma unroll
                    for (int v = 0; v < 2; ++v)
                        acc[u][v] = (f32x4){0.f, 0.f, 0.f, 0.f};
            }

            // 4 independent 4-deep MFMA chains (one per (u,v) tile)
            #pragma unroll
            for (int kkl = 0; kkl < 4; ++kkl) {
                #pragma unroll
                for (int u = 0; u < 2; ++u)
                    #pragma unroll
                    for (int v = 0; v < 2; ++v)
                        acc[u][v] = __builtin_amdgcn_mfma_f32_16x16x32_bf16(
                            as_s8(a[kkl]), as_s8(bfrag[u][v][kkl]), acc[u][v], 0, 0, 0);
            }

            // hi wave: hand partials to partner (rows 0,1 x 4 cols = 2xb128)
            if (hi && g == 0) {
                pbuf[wp][0][l16] = make_float4(acc[0][0][0], acc[0][0][1],
                                               acc[0][1][0], acc[0][1][1]);
                pbuf[wp][1][l16] = make_float4(acc[1][0][0], acc[1][0][1],
                                               acc[1][1][0], acc[1][1][1]);
            }

            // prefetch sv for t+1 (uniform-address, static LDS)
            {
                const int tn = (t + 1 < T) ? t + 1 : 0;
                svc = p ? seq2[tn] : xall[tn];
            }
            __syncthreads();   // partials visible

            if (hi == 0) {
                float h[2][2][2];   // [u][v][row]
                #pragma unroll
                for (int u = 0; u < 2; ++u) {
                    const float4 pp = pbuf[wp][u][l16];   // broadcast across g
                    h[u][0][0] = fast_tanh(acc[u][0][0] + pp.x);
                    h[u][0][1] = fast_tanh(acc[u][0][1] + pp.y);
                    h[u][1][0] = fast_tanh(acc[u][1][0] + pp.z);
                    h[u][1][1] = fast_tanh(acc[u][1][1] + pp.w);
                }
                unsigned pk[2][2];
                #pragma unroll
                for (int u = 0; u < 2; ++u)
                    #pragma unroll
                    for (int m = 0; m < 2; ++m)
                        asm("v_cvt_pk_bf16_f32 %0, %1, %2"
                            : "=v"(pk[u][m]) : "v"(h[u][0][m]), "v"(h[u][1][m]));
                if (g == 0) {
                    #pragma unroll
                    for (int u = 0; u < 2; ++u) {
                        *(unsigned int*)(hnxt + wr_off[u][0]) = pk[u][0];
                        *(unsigned int*)(hnxt + wr_off[u][1]) = pk[u][1];
                    }
                    if (t == T - 1) {
                        #pragma unroll
                        for (int u = 0; u < 2; ++u) {
                            const int colb = wp * 64 + u * 32 + 2 * l16;
                            if (p == 0) {
                                seq2[colb]     = make_float2(h[u][0][0], h[u][0][1]);
                                seq2[colb + 1] = make_float2(h[u][1][0], h[u][1][1]);
                            } else {
                                *(float2*)&h2out[(b0 + 0) * 256 + colb] =
                                    make_float2(h[u][0][0], h[u][1][0]);
                                *(float2*)&h2out[(b0 + 1) * 256 + colb] =
                                    make_float2(h[u][0][1], h[u][1][1]);
                            }
                        }
                    }
                }
            }
            __syncthreads();   // h buffer ready for t+1
        }
    }
}

// Tiny MLP head: one block per batch row, 128 threads.
__global__ __launch_bounds__(128) void mlp_kernel(
    const float* __restrict__ h2,
    const float* __restrict__ Wd1, const float* __restrict__ bd1,
    const float* __restrict__ Wd2, const float* __restrict__ bd2,
    const float* __restrict__ Wd3, const float* __restrict__ bd3,
    const float* __restrict__ Wd4, const float* __restrict__ bd4,
    float* __restrict__ out)
{
    const int b   = blockIdx.x;
    const int tid = threadIdx.x;

    __shared__ float hin[256];
    __shared__ float z1[128];
    __shared__ float z2[64];
    __shared__ float z3[32];

    hin[tid]       = h2[b * 256 + tid];
    hin[tid + 128] = h2[b * 256 + tid + 128];
    __syncthreads();

    {
        float a = bd1[tid];
#pragma unroll 8
        for (int i = 0; i < 256; ++i) a += hin[i] * Wd1[i * 128 + tid];
        z1[tid] = fmaxf(a, 0.0f);
    }
    __syncthreads();
    if (tid < 64) {
        float a = bd2[tid];
#pragma unroll 8
        for (int i = 0; i < 128; ++i) a += z1[i] * Wd2[i * 64 + tid];
        z2[tid] = fmaxf(a, 0.0f);
    }
    __syncthreads();
    if (tid < 32) {
        float a = bd3[tid];
#pragma unroll 8
        for (int i = 0; i < 64; ++i) a += z2[i] * Wd3[i * 32 + tid];
        z3[tid] = fmaxf(a, 0.0f);
    }
    __syncthreads();
    if (tid < NCLS) {
        float a = bd4[tid];
#pragma unroll
        for (int i = 0; i < 32; ++i) a += z3[i] * Wd4[i * NCLS + tid];
        out[b * NCLS + tid] = a;
    }
}

extern "C" void kernel_launch(void* const* d_in, const int* in_sizes, int n_in,
                              void* d_out, int out_size, void* d_ws, size_t ws_size,
                              hipStream_t stream) {
    const float* x   = (const float*)d_in[0];
    const float* W1  = (const float*)d_in[1];
    const float* U1  = (const float*)d_in[2];
    const float* b1  = (const float*)d_in[3];
    const float* W2  = (const float*)d_in[4];
    const float* U2  = (const float*)d_in[5];
    const float* b2  = (const float*)d_in[6];
    const float* Wd1 = (const float*)d_in[7];
    const float* bd1 = (const float*)d_in[8];
    const float* Wd2 = (const float*)d_in[9];
    const float* bd2 = (const float*)d_in[10];
    const float* Wd3 = (const float*)d_in[11];
    const float* bd3 = (const float*)d_in[12];
    const float* Wd4 = (const float*)d_in[13];
    const float* bd4 = (const float*)d_in[14];

    float* out = (float*)d_out;
    float* h2  = (float*)d_ws;        // 512*256 fp32

    rnn_fused_kernel<<<256, 512, 0, stream>>>(x, W1, U1, b1, W2, U2, b2, h2);
    mlp_kernel<<<512, 128, 0, stream>>>(h2, Wd1, bd1, Wd2, bd2, Wd3, bd3, Wd4, bd4, out);
}